// Round 8
// baseline (318.207 us; speedup 1.0000x reference)
//
#include <hip/hip_runtime.h>
#include <hip/hip_bf16.h>
#include <math.h>

// GCN: coarse bucket sort (512 nodes/bucket) -> per-bucket exact CSR ->
// wave-per-node pull aggregation (bf16 features, fp32 accum), dense layers
// fused into epilogues. Layer-2 feature dim split into two 3.2MB planar
// passes so the random-gather working set fits per-XCD L2 (4MB); gather
// loops 2-way unrolled for 64 edges in flight per wave.

#define CW    512
#define CSH   9
#define MAXBUKC 256   // n <= 131072 (17-bit src packing)

static inline int cdiv(int a, int b) { return (a + b - 1) / b; }

// bf16 helpers (RNE)
__device__ inline unsigned int bf16_rn(float f) {
    unsigned int u = __float_as_uint(f);
    return (u + 0x7fffu + ((u >> 16) & 1u)) >> 16;
}
#define BLO(u) __uint_as_float((u) << 16)
#define BHI(u) __uint_as_float((u) & 0xffff0000u)

#define UNPACK_ADD(A, V) \
    A[0] += BLO(V.x); A[1] += BHI(V.x); \
    A[2] += BLO(V.y); A[3] += BHI(V.y); \
    A[4] += BLO(V.z); A[5] += BHI(V.z); \
    A[6] += BLO(V.w); A[7] += BHI(V.w);

// ---------------- bucket build ----------------

__global__ void __launch_bounds__(256) k_bhist(const int* __restrict__ dst,
                                               int* __restrict__ bcnt, int e, int nbuk) {
    __shared__ int lh[MAXBUKC];
    for (int b = threadIdx.x; b < nbuk; b += 256) lh[b] = 0;
    __syncthreads();
    int base = blockIdx.x * 4096;
#pragma unroll
    for (int j = 0; j < 16; j++) {
        int i = base + j * 256 + threadIdx.x;
        if (i < e) atomicAdd(&lh[dst[i] >> CSH], 1);
    }
    __syncthreads();
    for (int b = threadIdx.x; b < nbuk; b += 256) {
        int c = lh[b];
        if (c) atomicAdd(&bcnt[b], c);
    }
}

__global__ void __launch_bounds__(256) k_bscan(const int* __restrict__ bcnt,
                                               int* __restrict__ boff, int* __restrict__ gcur,
                                               int nbuk, int e) {
    __shared__ int sh[256];
    int t = threadIdx.x;
    int v = (t < nbuk) ? bcnt[t] : 0;
    sh[t] = v;
    __syncthreads();
    for (int o = 1; o < 256; o <<= 1) {
        int u = (t >= o) ? sh[t - o] : 0;
        __syncthreads();
        sh[t] += u;
        __syncthreads();
    }
    if (t < nbuk) { int ex = sh[t] - v; boff[t] = ex; gcur[t] = ex; }
    if (t == 0) boff[nbuk] = e;
}

__global__ void __launch_bounds__(256) k_bscatter(const int* __restrict__ src,
                                                  const int* __restrict__ dst,
                                                  int* __restrict__ gcur,
                                                  int* __restrict__ ebuf, int e, int nbuk) {
    __shared__ int lh[MAXBUKC];
    __shared__ int lb[MAXBUKC];
    int db[32];
    for (int b = threadIdx.x; b < nbuk; b += 256) lh[b] = 0;
    __syncthreads();
    int base = blockIdx.x * 8192;
#pragma unroll
    for (int j = 0; j < 32; j++) {
        int i = base + j * 256 + threadIdx.x;
        db[j] = (i < e) ? dst[i] : 0;
        if (i < e) atomicAdd(&lh[db[j] >> CSH], 1);
    }
    __syncthreads();
    for (int b = threadIdx.x; b < nbuk; b += 256) {
        int c = lh[b];
        lb[b] = c ? atomicAdd(&gcur[b], c) : 0;
        lh[b] = 0;
    }
    __syncthreads();
#pragma unroll
    for (int j = 0; j < 32; j++) {
        int i = base + j * 256 + threadIdx.x;
        if (i < e) {
            int d = db[j];
            int s = src[i];
            int b = d >> CSH;
            int r = atomicAdd(&lh[b], 1);
            ebuf[lb[b] + r] = ((d & (CW - 1)) << 17) | s;
        }
    }
}

// ---------------- per-bucket exact CSR + dinv ----------------

__global__ void __launch_bounds__(CW) k_csr2(const int* __restrict__ ebuf,
                                             const int* __restrict__ boff,
                                             int* __restrict__ rowstart,
                                             int* __restrict__ csr_src,
                                             float* __restrict__ dinv, int n, int e) {
    __shared__ int cnt[CW];
    __shared__ int offs[CW];
    int t = threadIdx.x;
    cnt[t] = 0;
    __syncthreads();
    int beg = boff[blockIdx.x], end = boff[blockIdx.x + 1];
    for (int k = beg + t; k < end; k += CW)
        atomicAdd(&cnt[ebuf[k] >> 17], 1);
    __syncthreads();
    int v = cnt[t];
    offs[t] = v;
    __syncthreads();
    for (int o = 1; o < CW; o <<= 1) {
        int u = (t >= o) ? offs[t - o] : 0;
        __syncthreads();
        offs[t] += u;
        __syncthreads();
    }
    int ex = offs[t] - v;
    int node = blockIdx.x * CW + t;
    if (node < n) {
        rowstart[node] = beg + ex;
        dinv[node] = rsqrtf((float)v + 1.0f);
    }
    cnt[t] = ex;
    __syncthreads();
    for (int k = beg + t; k < end; k += CW) {
        int pv = ebuf[k];
        int dl = pv >> 17, s = pv & 0x1FFFF;
        int r = atomicAdd(&cnt[dl], 1);
        csr_src[beg + r] = s;
    }
    if (blockIdx.x == 0 && t == 0) rowstart[n] = e;
}

// ---------------- pre-scale + bf16 pack ----------------

__global__ void __launch_bounds__(256) k_xscale(const float* __restrict__ x,
                                                const float* __restrict__ dinv,
                                                unsigned int* __restrict__ xs, int n4) {
    int i = blockIdx.x * blockDim.x + threadIdx.x;
    if (i >= n4) return;
    float dd = dinv[i >> 2];
    float4 v = ((const float4*)x)[i];
    uint2 o;
    o.x = bf16_rn(v.x * dd) | (bf16_rn(v.y * dd) << 16);
    o.y = bf16_rn(v.z * dd) | (bf16_rn(v.w * dd) << 16);
    ((uint2*)xs)[i] = o;
}

// ---------------- Layer 1: agg(xs,16) -> dense 16->32 relu -> planar h1 ----------------
// 2 lanes/edge, 32 edges per round, unrolled x2 -> 64 loads in flight.

__global__ void __launch_bounds__(256) k_pull16_d(const int* __restrict__ rowstart,
                                                  const int* __restrict__ csr_src,
                                                  const float* __restrict__ dinv,
                                                  const unsigned int* __restrict__ xs,
                                                  const float* __restrict__ W1,
                                                  const float* __restrict__ b1,
                                                  unsigned short* __restrict__ h1lo,
                                                  unsigned short* __restrict__ h1hi, int n) {
    int wid = (blockIdx.x * blockDim.x + threadIdx.x) >> 6;
    if (wid >= n) return;
    int lane = threadIdx.x & 63;
    int half = lane & 1;
    int beg = rowstart[wid], end = rowstart[wid + 1];
    const uint4* x4 = (const uint4*)xs;   // 2 uint4 per node row
    float acc[8], ac1[8];
#pragma unroll
    for (int i = 0; i < 8; i++) { acc[i] = 0.f; ac1[i] = 0.f; }
    int k = beg + (lane >> 1);
    for (; k + 32 < end; k += 64) {
        int s0 = __builtin_nontemporal_load(csr_src + k);
        int s1 = __builtin_nontemporal_load(csr_src + k + 32);
        uint4 v0 = x4[(size_t)s0 * 2 + half];
        uint4 v1 = x4[(size_t)s1 * 2 + half];
        UNPACK_ADD(acc, v0);
        UNPACK_ADD(ac1, v1);
    }
    if (k < end) {
        int s0 = __builtin_nontemporal_load(csr_src + k);
        uint4 v0 = x4[(size_t)s0 * 2 + half];
        UNPACK_ADD(acc, v0);
    }
#pragma unroll
    for (int i = 0; i < 8; i++) acc[i] += ac1[i];
#pragma unroll
    for (int off = 2; off < 64; off <<= 1)
#pragma unroll
        for (int i = 0; i < 8; i++) acc[i] += __shfl_xor(acc[i], off);
    float dd = dinv[wid];
    {
        uint4 sv = x4[(size_t)wid * 2 + half];
        UNPACK_ADD(acc, sv);
    }
#pragma unroll
    for (int i = 0; i < 8; i++) acc[i] *= dd;
    int col = lane & 31;
    float o = b1[col];
#pragma unroll
    for (int kk = 0; kk < 16; kk++) {
        float av = __shfl(acc[kk & 7], (lane & 62) | (kk >> 3));
        o += av * W1[kk * 32 + col];
    }
    if (lane < 32) {
        unsigned short hv = (unsigned short)bf16_rn(fmaxf(o, 0.f) * dd);
        if (col < 16) h1lo[(size_t)wid * 16 + col] = hv;
        else          h1hi[(size_t)wid * 16 + (col - 16)] = hv;
    }
}

// ---------------- Layer 2 pass A: agg lo plane -> agg_lo fp32 ----------------

__global__ void __launch_bounds__(256) k_p2a(const int* __restrict__ rowstart,
                                             const int* __restrict__ csr_src,
                                             const float* __restrict__ dinv,
                                             const unsigned int* __restrict__ h1lo,
                                             float* __restrict__ agg_lo, int n) {
    int wid = (blockIdx.x * blockDim.x + threadIdx.x) >> 6;
    if (wid >= n) return;
    int lane = threadIdx.x & 63;
    int half = lane & 1;
    int beg = rowstart[wid], end = rowstart[wid + 1];
    const uint4* h4 = (const uint4*)h1lo;
    float acc[8], ac1[8];
#pragma unroll
    for (int i = 0; i < 8; i++) { acc[i] = 0.f; ac1[i] = 0.f; }
    int k = beg + (lane >> 1);
    for (; k + 32 < end; k += 64) {
        int s0 = __builtin_nontemporal_load(csr_src + k);
        int s1 = __builtin_nontemporal_load(csr_src + k + 32);
        uint4 v0 = h4[(size_t)s0 * 2 + half];
        uint4 v1 = h4[(size_t)s1 * 2 + half];
        UNPACK_ADD(acc, v0);
        UNPACK_ADD(ac1, v1);
    }
    if (k < end) {
        int s0 = __builtin_nontemporal_load(csr_src + k);
        uint4 v0 = h4[(size_t)s0 * 2 + half];
        UNPACK_ADD(acc, v0);
    }
#pragma unroll
    for (int i = 0; i < 8; i++) acc[i] += ac1[i];
#pragma unroll
    for (int off = 2; off < 64; off <<= 1)
#pragma unroll
        for (int i = 0; i < 8; i++) acc[i] += __shfl_xor(acc[i], off);
    float dd = dinv[wid];
    {
        uint4 sv = h4[(size_t)wid * 2 + half];
        UNPACK_ADD(acc, sv);
    }
#pragma unroll
    for (int i = 0; i < 8; i++) acc[i] *= dd;
    if (lane < 2) {
        float4 f0 = make_float4(acc[0], acc[1], acc[2], acc[3]);
        float4 f1 = make_float4(acc[4], acc[5], acc[6], acc[7]);
        ((float4*)agg_lo)[(size_t)wid * 4 + lane * 2]     = f0;
        ((float4*)agg_lo)[(size_t)wid * 4 + lane * 2 + 1] = f1;
    }
}

// ---------------- Layer 2 pass B: agg hi plane + dense 32->64 relu + W3 -> t2 ----------------

__global__ void __launch_bounds__(256) k_p2b(const int* __restrict__ rowstart,
                                             const int* __restrict__ csr_src,
                                             const float* __restrict__ dinv,
                                             const unsigned int* __restrict__ h1hi,
                                             const float* __restrict__ agg_lo,
                                             const float* __restrict__ W2,
                                             const float* __restrict__ b2,
                                             const float* __restrict__ W3,
                                             float* __restrict__ t2, int n) {
    int wid = (blockIdx.x * blockDim.x + threadIdx.x) >> 6;
    if (wid >= n) return;
    int lane = threadIdx.x & 63;
    int half = lane & 1;
    int beg = rowstart[wid], end = rowstart[wid + 1];
    const uint4* h4 = (const uint4*)h1hi;
    float acc[8], ac1[8];
#pragma unroll
    for (int i = 0; i < 8; i++) { acc[i] = 0.f; ac1[i] = 0.f; }
    int k = beg + (lane >> 1);
    for (; k + 32 < end; k += 64) {
        int s0 = __builtin_nontemporal_load(csr_src + k);
        int s1 = __builtin_nontemporal_load(csr_src + k + 32);
        uint4 v0 = h4[(size_t)s0 * 2 + half];
        uint4 v1 = h4[(size_t)s1 * 2 + half];
        UNPACK_ADD(acc, v0);
        UNPACK_ADD(ac1, v1);
    }
    if (k < end) {
        int s0 = __builtin_nontemporal_load(csr_src + k);
        uint4 v0 = h4[(size_t)s0 * 2 + half];
        UNPACK_ADD(acc, v0);
    }
#pragma unroll
    for (int i = 0; i < 8; i++) acc[i] += ac1[i];
#pragma unroll
    for (int off = 2; off < 64; off <<= 1)
#pragma unroll
        for (int i = 0; i < 8; i++) acc[i] += __shfl_xor(acc[i], off);
    float dd = dinv[wid];
    {
        uint4 sv = h4[(size_t)wid * 2 + half];
        UNPACK_ADD(acc, sv);
    }
#pragma unroll
    for (int i = 0; i < 8; i++) acc[i] *= dd;
    // feats 0..15 from pass A (already *dd): lane l holds feat (l&15)
    float vlo = agg_lo[(size_t)wid * 16 + (lane & 15)];
    float o = b2[lane];
#pragma unroll
    for (int kk = 0; kk < 16; kk++)
        o += __shfl(vlo, kk) * W2[kk * 64 + lane];
#pragma unroll
    for (int kk = 0; kk < 16; kk++) {
        float av = __shfl(acc[kk & 7], (lane & 62) | (kk >> 3));
        o += av * W2[(kk + 16) * 64 + lane];
    }
    float p = fmaxf(o, 0.f) * W3[lane];
#pragma unroll
    for (int off = 1; off < 64; off <<= 1) p += __shfl_xor(p, off);
    if (lane == 0) t2[wid] = p * dd;
}

// ---------------- Layer 3: scalar pull + bias + sigmoid ----------------

__global__ void __launch_bounds__(256) k_pull1_sig(const int* __restrict__ rowstart,
                                                   const int* __restrict__ csr_src,
                                                   const float* __restrict__ dinv,
                                                   const float* __restrict__ t2,
                                                   const float* __restrict__ b3,
                                                   float* __restrict__ out, int n) {
    int wid = (blockIdx.x * blockDim.x + threadIdx.x) >> 6;
    if (wid >= n) return;
    int lane = threadIdx.x & 63;
    int beg = rowstart[wid], end = rowstart[wid + 1];
    float acc = 0.f;
    for (int k = beg + lane; k < end; k += 64)
        acc += t2[__builtin_nontemporal_load(csr_src + k)];
#pragma unroll
    for (int off = 1; off < 64; off <<= 1) acc += __shfl_xor(acc, off);
    if (lane == 0) {
        float v = (acc + t2[wid]) * dinv[wid] + b3[0];
        out[wid] = 1.0f / (1.0f + expf(-v));
    }
}

// ---------------- launch ----------------

extern "C" void kernel_launch(void* const* d_in, const int* in_sizes, int n_in,
                              void* d_out, int out_size, void* d_ws, size_t ws_size,
                              hipStream_t stream) {
    const float* x  = (const float*)d_in[0];
    const int*   ei = (const int*)d_in[1];
    const float* W1 = (const float*)d_in[2];
    const float* b1 = (const float*)d_in[3];
    const float* W2 = (const float*)d_in[4];
    const float* b2 = (const float*)d_in[5];
    const float* W3 = (const float*)d_in[6];
    const float* b3 = (const float*)d_in[7];

    const int n = in_sizes[0] / 16;
    const int e = in_sizes[1] / 2;
    const int* src = ei;
    const int* dst = ei + e;
    const int nbuk = cdiv(n, CW);   // 196 for n=100000

    auto rup = [](size_t v) { return (v + 15) & ~(size_t)15; };
    char* wp = (char*)d_ws;
    auto alloc = [&](size_t elems) { void* p = wp; wp += rup(elems) * 4; return p; };
    int*   bcnt     = (int*)  alloc(MAXBUKC);
    int*   boff     = (int*)  alloc(MAXBUKC + 1);
    int*   gcur     = (int*)  alloc(MAXBUKC);
    float* dinv     = (float*)alloc(n);
    int*   rowstart = (int*)  alloc(n + 1);
    int*   ebuf     = (int*)  alloc(e);
    int*   csr_src  = (int*)  alloc(e);
    unsigned int* xs   = (unsigned int*)alloc((size_t)8 * n);   // 16 bf16 / node
    unsigned int* h1lo = (unsigned int*)alloc((size_t)8 * n);   // 16 bf16 / node
    unsigned int* h1hi = (unsigned int*)alloc((size_t)8 * n);   // 16 bf16 / node
    float* agg_lo   = (float*)alloc((size_t)16 * n);
    float* t2       = (float*)alloc(n);

    float* out = (float*)d_out;
    const int B = 256;
    const int pullGrid = cdiv(n * 64, B);

    hipMemsetAsync(bcnt, 0, MAXBUKC * 4, stream);
    k_bhist<<<cdiv(e, 4096), B, 0, stream>>>(dst, bcnt, e, nbuk);
    k_bscan<<<1, 256, 0, stream>>>(bcnt, boff, gcur, nbuk, e);
    k_bscatter<<<cdiv(e, 8192), B, 0, stream>>>(src, dst, gcur, ebuf, e, nbuk);
    k_csr2<<<nbuk, CW, 0, stream>>>(ebuf, boff, rowstart, csr_src, dinv, n, e);
    k_xscale<<<cdiv(n * 4, B), B, 0, stream>>>(x, dinv, xs, n * 4);

    k_pull16_d<<<pullGrid, B, 0, stream>>>(rowstart, csr_src, dinv, xs, W1, b1,
                                           (unsigned short*)h1lo, (unsigned short*)h1hi, n);
    k_p2a<<<pullGrid, B, 0, stream>>>(rowstart, csr_src, dinv, h1lo, agg_lo, n);
    k_p2b<<<pullGrid, B, 0, stream>>>(rowstart, csr_src, dinv, h1hi, agg_lo,
                                      W2, b2, W3, t2, n);
    k_pull1_sig<<<pullGrid, B, 0, stream>>>(rowstart, csr_src, dinv, t2, b3, out, n);
}